// Round 1
// baseline (1974.601 us; speedup 1.0000x reference)
//
#include <hip/hip_runtime.h>

#define NN 100000
#define NE 1600000
#define NG 512
#define HD 128

// ---------------- dtype detect: int64 vs int32 edge_index ----------------
__global__ void detect_kernel(const unsigned* __restrict__ ei, int* __restrict__ flag) {
    // If edge_index is int64 (little-endian), odd 32-bit words are high words == 0.
    unsigned v = ei[threadIdx.x * 2 + 1];
    unsigned long long m = __ballot(v != 0u);
    if (threadIdx.x == 0) flag[0] = (m == 0ull) ? 1 : 0;
}

__device__ __forceinline__ int load_idx(const void* p, long long i, int is64) {
    return is64 ? (int)((const long long*)p)[i] : ((const int*)p)[i];
}

// ---------------- CSR build ----------------
__global__ void count_deg_kernel(const void* __restrict__ eiv, const float* __restrict__ ew,
                                 int* __restrict__ counts, float* __restrict__ deg,
                                 const int* __restrict__ flag, int E) {
    int i = blockIdx.x * 256 + threadIdx.x;
    if (i >= E) return;
    int is64 = *flag;
    int r = load_idx(eiv, i, is64);
    atomicAdd(&counts[r], 1);
    atomicAdd(&deg[r], ew[i]);
}

__global__ __launch_bounds__(256) void scan_pass1(const int* __restrict__ counts,
                                                  int* __restrict__ partials, int n) {
    __shared__ int red[256];
    int t = threadIdx.x;
    int base = blockIdx.x * 1024;
    int s = 0;
#pragma unroll
    for (int j = 0; j < 4; j++) {
        int i = base + t * 4 + j;
        if (i < n) s += counts[i];
    }
    red[t] = s;
    __syncthreads();
    for (int off = 128; off > 0; off >>= 1) {
        if (t < off) red[t] += red[t + off];
        __syncthreads();
    }
    if (t == 0) partials[blockIdx.x] = red[0];
}

__global__ void scan_pass2(int* __restrict__ partials, int nb) {
    if (threadIdx.x == 0 && blockIdx.x == 0) {
        int run = 0;
        for (int b = 0; b < nb; b++) { int v = partials[b]; partials[b] = run; run += v; }
    }
}

__global__ __launch_bounds__(256) void scan_pass3(const int* __restrict__ counts,
                                                  const int* __restrict__ partials,
                                                  int* __restrict__ rowptr, int* __restrict__ cursor, int n) {
    __shared__ int red[256];
    int t = threadIdx.x;
    int base = blockIdx.x * 1024;
    int v[4];
    int s = 0;
#pragma unroll
    for (int j = 0; j < 4; j++) {
        int i = base + t * 4 + j;
        v[j] = (i < n) ? counts[i] : 0;
        s += v[j];
    }
    red[t] = s;
    __syncthreads();
    for (int off = 1; off < 256; off <<= 1) {
        int addv = (t >= off) ? red[t - off] : 0;
        __syncthreads();
        red[t] += addv;
        __syncthreads();
    }
    int run = partials[blockIdx.x] + red[t] - s;  // exclusive prefix
#pragma unroll
    for (int j = 0; j < 4; j++) {
        int i = base + t * 4 + j;
        if (i < n) {
            rowptr[i] = run;
            cursor[i] = run;
            run += v[j];
            if (i == n - 1) rowptr[n] = run;
        }
    }
}

__global__ void scatter_kernel(const void* __restrict__ eiv, const float* __restrict__ ew,
                               int* __restrict__ cursor, int* __restrict__ ccol, float* __restrict__ cwt,
                               const int* __restrict__ flag, int E) {
    int i = blockIdx.x * 256 + threadIdx.x;
    if (i >= E) return;
    int is64 = *flag;
    int r = load_idx(eiv, i, is64);
    int c = load_idx(eiv, (long long)E + i, is64);
    int pos = atomicAdd(&cursor[r], 1);
    ccol[pos] = c;
    cwt[pos] = ew[i];
}

__global__ void dscale_kernel(float* __restrict__ deg, int n) {
    int i = blockIdx.x * 256 + threadIdx.x;
    if (i >= n) return;
    float d = fmaxf(deg[i], 1e-12f);
    deg[i] = 0.5f / d;  // deg_inv / (1+mu), mu=1
}

// ---------------- fp32 tiled GEMM: C[n,OC] = epi(A[n,K] @ W[K,OC] + b) ----------------
// EPI: 0 = relu; 1 = BatchNorm eval then *0.5 (produces h' = mu*h/(1+mu))
template <int K, int OC, int EPI>
__global__ __launch_bounds__(256) void gemm_kernel(const float* __restrict__ A, const float* __restrict__ W,
                                                   const float* __restrict__ bias, float* __restrict__ C, int nrows,
                                                   const float* __restrict__ bn_g, const float* __restrict__ bn_b,
                                                   const float* __restrict__ bn_m, const float* __restrict__ bn_v) {
    constexpr int CW = OC / 16;  // cols per thread (8 for OC=128, 4 for OC=64)
    constexpr int KC = 32;
    __shared__ float Alds[64 * (K + 1)];
    __shared__ float Wlds[KC * OC];
    const int t = threadIdx.x;
    const int tx = t & 15, ty = t >> 4;
    const int rowbase = blockIdx.x * 64;

    for (int i = t; i < 64 * K; i += 256) {
        int n = i / K, k = i - n * K;
        int gn = rowbase + n;
        Alds[n * (K + 1) + k] = (gn < nrows) ? A[(long long)gn * K + k] : 0.0f;
    }
    float acc[4][CW];
#pragma unroll
    for (int i = 0; i < 4; i++)
#pragma unroll
        for (int j = 0; j < CW; j++) acc[i][j] = 0.f;

    for (int kc = 0; kc < K; kc += KC) {
        __syncthreads();
        for (int i = t; i < KC * OC; i += 256) Wlds[i] = W[kc * OC + i];
        __syncthreads();
#pragma unroll
        for (int k = 0; k < KC; k++) {
            float a_[4];
#pragma unroll
            for (int i = 0; i < 4; i++) a_[i] = Alds[(ty * 4 + i) * (K + 1) + kc + k];
            float w_[CW];
            const float4* wp = (const float4*)&Wlds[k * OC + tx * CW];
            float4 w0 = wp[0];
            w_[0] = w0.x; w_[1] = w0.y; w_[2] = w0.z; w_[3] = w0.w;
            if (CW == 8) {
                float4 w1 = wp[1];
                w_[4] = w1.x; w_[5] = w1.y; w_[6] = w1.z; w_[7] = w1.w;
            }
#pragma unroll
            for (int i = 0; i < 4; i++)
#pragma unroll
                for (int j = 0; j < CW; j++) acc[i][j] += a_[i] * w_[j];
        }
    }
#pragma unroll
    for (int i = 0; i < 4; i++) {
        int gn = rowbase + ty * 4 + i;
        if (gn >= nrows) continue;
#pragma unroll
        for (int j = 0; j < CW; j++) {
            int c = tx * CW + j;
            float v = acc[i][j] + bias[c];
            if (EPI == 0) {
                v = fmaxf(v, 0.f);
            } else {
                v = (v - bn_m[c]) * rsqrtf(bn_v[c] + 1e-5f) * bn_g[c] + bn_b[c];
                v *= 0.5f;  // mu/(1+mu)
            }
            C[(long long)gn * OC + c] = v;
        }
    }
}

// ---------------- DEQ propagation step: z_out = dscale[n] * sum_e w*z_in[col] + hp[n] ----------------
__global__ __launch_bounds__(128) void deq_step(const float* __restrict__ zin, float* __restrict__ zout,
                                                const float* __restrict__ hp, const float* __restrict__ dscale,
                                                const int* __restrict__ rowptr, const int* __restrict__ ccol,
                                                const float* __restrict__ cwt) {
    const int n = blockIdx.x;
    const int t = threadIdx.x;
    const int s = rowptr[n], e = rowptr[n + 1];
    float acc = 0.f;
    int i = s;
    for (; i + 1 < e; i += 2) {
        int c0 = ccol[i], c1 = ccol[i + 1];
        float w0 = cwt[i], w1 = cwt[i + 1];
        float z0 = zin[(long long)c0 * HD + t];
        float z1 = zin[(long long)c1 * HD + t];
        acc += w0 * z0 + w1 * z1;
    }
    if (i < e) {
        acc += cwt[i] * zin[(long long)ccol[i] * HD + t];
    }
    zout[(long long)n * HD + t] = acc * dscale[n] + hp[(long long)n * HD + t];
}

// ---------------- pool over sorted batch ----------------
__global__ __launch_bounds__(128) void pool_kernel(const float* __restrict__ z, const void* __restrict__ batchv,
                                                   const int* __restrict__ flag, float* __restrict__ gpool, int n) {
    const int t = threadIdx.x;
    int n0 = blockIdx.x * 64;
    int n1 = min(n0 + 64, n);
    int is64 = *flag;
    float run = 0.f;
    int cur = -1;
    for (int i = n0; i < n1; i++) {
        int b = load_idx(batchv, i, is64);
        if (b != cur) {
            if (cur >= 0) atomicAdd(&gpool[cur * HD + t], run);
            run = 0.f;
            cur = b;
        }
        run += z[(long long)i * HD + t];
    }
    if (cur >= 0) atomicAdd(&gpool[cur * HD + t], run);
}

// ---------------- graph head: 2x FC + final + log_softmax ----------------
__global__ __launch_bounds__(128) void graph_kernel(const float* __restrict__ gpool, const float* __restrict__ gfc_w,
                                                    const float* __restrict__ gfc_b, const float* __restrict__ fw,
                                                    const float* __restrict__ fb, float* __restrict__ out) {
    __shared__ float buf[HD];
    __shared__ float o[10];
    __shared__ float ls;
    const int g = blockIdx.x, t = threadIdx.x;
    buf[t] = gpool[g * HD + t];
    __syncthreads();
    for (int L = 0; L < 2; L++) {
        const float* w = gfc_w + L * HD * HD;
        float s = gfc_b[L * HD + t];
        for (int k = 0; k < HD; k++) s += buf[k] * w[k * HD + t];
        s = fmaxf(s, 0.f);
        __syncthreads();
        buf[t] = s;
        __syncthreads();
    }
    if (t < 10) {
        float s = fb[t];
        for (int k = 0; k < HD; k++) s += buf[k] * fw[k * 10 + t];
        o[t] = s;
    }
    __syncthreads();
    if (t == 0) {
        float m = o[0];
        for (int i = 1; i < 10; i++) m = fmaxf(m, o[i]);
        float se = 0.f;
        for (int i = 0; i < 10; i++) se += expf(o[i] - m);
        ls = m + logf(se);
    }
    __syncthreads();
    if (t < 10) out[g * 10 + t] = o[t] - ls;
}

extern "C" void kernel_launch(void* const* d_in, const int* in_sizes, int n_in,
                              void* d_out, int out_size, void* d_ws, size_t ws_size,
                              hipStream_t stream) {
    const float* x = (const float*)d_in[0];
    const void* eiv = d_in[1];
    const float* ew = (const float*)d_in[2];
    const void* batchv = d_in[3];
    const float* mlp_w1 = (const float*)d_in[4];
    const float* mlp_b1 = (const float*)d_in[5];
    const float* mlp_w2 = (const float*)d_in[6];
    const float* mlp_b2 = (const float*)d_in[7];
    const float* mlp_w3 = (const float*)d_in[8];
    const float* mlp_b3 = (const float*)d_in[9];
    const float* bn_g = (const float*)d_in[10];
    const float* bn_b = (const float*)d_in[11];
    const float* bn_m = (const float*)d_in[12];
    const float* bn_v = (const float*)d_in[13];
    const float* fc_w = (const float*)d_in[14];
    const float* fc_b = (const float*)d_in[15];
    const float* gfc_w = (const float*)d_in[16];
    const float* gfc_b = (const float*)d_in[17];
    const float* fin_w = (const float*)d_in[18];
    const float* fin_b = (const float*)d_in[19];
    float* out = (float*)d_out;

    char* ws = (char*)d_ws;
    size_t off = 0;
    auto alloc = [&](size_t bytes) -> void* {
        void* p = ws + off;
        off = (off + bytes + 255) & ~(size_t)255;
        return p;
    };
    float* hp = (float*)alloc((size_t)NN * HD * 4);
    float* zb1 = (float*)alloc((size_t)NN * HD * 4);
    float* zb2 = (float*)alloc((size_t)NN * HD * 4);
    int* ccol = (int*)alloc((size_t)NE * 4);
    float* cwt = (float*)alloc((size_t)NE * 4);
    int* rowptr = (int*)alloc((size_t)(NN + 1) * 4);
    int* cursor = (int*)alloc((size_t)NN * 4);
    int* counts = (int*)alloc((size_t)NN * 4);
    float* deg = (float*)alloc((size_t)NN * 4);  // becomes dscale in-place
    int* partials = (int*)alloc(1024 * 4);
    float* gpool = (float*)alloc((size_t)NG * HD * 4);
    int* flag = (int*)alloc(256);

    hipMemsetAsync(counts, 0, (size_t)NN * 4, stream);
    hipMemsetAsync(deg, 0, (size_t)NN * 4, stream);
    hipMemsetAsync(gpool, 0, (size_t)NG * HD * 4, stream);

    detect_kernel<<<1, 64, 0, stream>>>((const unsigned*)eiv, flag);
    count_deg_kernel<<<(NE + 255) / 256, 256, 0, stream>>>(eiv, ew, counts, deg, flag, NE);
    const int NB = (NN + 1023) / 1024;
    scan_pass1<<<NB, 256, 0, stream>>>(counts, partials, NN);
    scan_pass2<<<1, 64, 0, stream>>>(partials, NB);
    scan_pass3<<<NB, 256, 0, stream>>>(counts, partials, rowptr, cursor, NN);
    scatter_kernel<<<(NE + 255) / 256, 256, 0, stream>>>(eiv, ew, cursor, ccol, cwt, flag, NE);
    dscale_kernel<<<(NN + 255) / 256, 256, 0, stream>>>(deg, NN);

    const int GB = (NN + 63) / 64;
    // MLP encoder: x -> relu -> relu -> BN -> *0.5 = h'
    gemm_kernel<128, 64, 0><<<GB, 256, 0, stream>>>(x, mlp_w1, mlp_b1, zb2, NN, nullptr, nullptr, nullptr, nullptr);
    gemm_kernel<64, 128, 0><<<GB, 256, 0, stream>>>(zb2, mlp_w2, mlp_b2, zb1, NN, nullptr, nullptr, nullptr, nullptr);
    gemm_kernel<128, 128, 1><<<GB, 256, 0, stream>>>(zb1, mlp_w3, mlp_b3, hp, NN, bn_g, bn_b, bn_m, bn_v);

    // DEQ: z1 = h' (analytic), then 9 propagation steps
    const float* zin = hp;
    float* zbufs[2] = {zb1, zb2};
    for (int it = 0; it < 9; it++) {
        float* zout = zbufs[it & 1];
        deq_step<<<NN, 128, 0, stream>>>(zin, zout, hp, deg, rowptr, ccol, cwt);
        zin = zout;
    }
    // zin == zb1 after 9 steps

    // node FC stack
    gemm_kernel<128, 128, 0><<<GB, 256, 0, stream>>>(zb1, fc_w, fc_b, hp, NN, nullptr, nullptr, nullptr, nullptr);
    gemm_kernel<128, 128, 0><<<GB, 256, 0, stream>>>(hp, fc_w + 128 * 128, fc_b + 128, zb2, NN, nullptr, nullptr, nullptr, nullptr);

    pool_kernel<<<(NN + 63) / 64, 128, 0, stream>>>(zb2, batchv, flag, gpool, NN);
    graph_kernel<<<NG, 128, 0, stream>>>(gpool, gfc_w, gfc_b, fin_w, fin_b, out);
}

// Round 2
// 1287.892 us; speedup vs baseline: 1.5332x; 1.5332x over previous
//
#include <hip/hip_runtime.h>

#define NN 100000
#define NE 1600000
#define NG 512
#define HD 128

typedef short short8 __attribute__((ext_vector_type(8)));
typedef float f32x4 __attribute__((ext_vector_type(4)));

__device__ __forceinline__ ushort f2b(float v) {
    uint u = __float_as_uint(v);
    u = (u + 0x7fffu + ((u >> 16) & 1u)) >> 16;
    return (ushort)u;
}
__device__ __forceinline__ uint pkbf(float a, float b) {
    return (uint)f2b(a) | ((uint)f2b(b) << 16);
}
__device__ __forceinline__ float blo(uint u) { return __uint_as_float(u << 16); }
__device__ __forceinline__ float bhi(uint u) { return __uint_as_float(u & 0xffff0000u); }

// ---------------- dtype detect: int64 vs int32 edge_index ----------------
__global__ void detect_kernel(const unsigned* __restrict__ ei, int* __restrict__ flag) {
    unsigned v = ei[threadIdx.x * 2 + 1];
    unsigned long long m = __ballot(v != 0u);
    if (threadIdx.x == 0) flag[0] = (m == 0ull) ? 1 : 0;
}

__device__ __forceinline__ int load_idx(const void* p, long long i, int is64) {
    return is64 ? (int)((const long long*)p)[i] : ((const int*)p)[i];
}

// ---------------- CSR build ----------------
__global__ void count_kernel(const void* __restrict__ eiv, int* __restrict__ counts,
                             const int* __restrict__ flag, int E) {
    int i = blockIdx.x * 256 + threadIdx.x;
    if (i >= E) return;
    int is64 = *flag;
    int r = load_idx(eiv, i, is64);
    atomicAdd(&counts[r], 1);
}

__global__ __launch_bounds__(256) void scan_pass1(const int* __restrict__ counts,
                                                  int* __restrict__ partials, int n) {
    __shared__ int red[256];
    int t = threadIdx.x;
    int base = blockIdx.x * 1024;
    int s = 0;
#pragma unroll
    for (int j = 0; j < 4; j++) {
        int i = base + t * 4 + j;
        if (i < n) s += counts[i];
    }
    red[t] = s;
    __syncthreads();
    for (int off = 128; off > 0; off >>= 1) {
        if (t < off) red[t] += red[t + off];
        __syncthreads();
    }
    if (t == 0) partials[blockIdx.x] = red[0];
}

__global__ void scan_pass2(int* __restrict__ partials, int nb) {
    if (threadIdx.x == 0 && blockIdx.x == 0) {
        int run = 0;
        for (int b = 0; b < nb; b++) { int v = partials[b]; partials[b] = run; run += v; }
    }
}

__global__ __launch_bounds__(256) void scan_pass3(const int* __restrict__ counts,
                                                  const int* __restrict__ partials,
                                                  int* __restrict__ rowptr, int* __restrict__ cursor, int n) {
    __shared__ int red[256];
    int t = threadIdx.x;
    int base = blockIdx.x * 1024;
    int v[4];
    int s = 0;
#pragma unroll
    for (int j = 0; j < 4; j++) {
        int i = base + t * 4 + j;
        v[j] = (i < n) ? counts[i] : 0;
        s += v[j];
    }
    red[t] = s;
    __syncthreads();
    for (int off = 1; off < 256; off <<= 1) {
        int addv = (t >= off) ? red[t - off] : 0;
        __syncthreads();
        red[t] += addv;
        __syncthreads();
    }
    int run = partials[blockIdx.x] + red[t] - s;  // exclusive prefix
#pragma unroll
    for (int j = 0; j < 4; j++) {
        int i = base + t * 4 + j;
        if (i < n) {
            rowptr[i] = run;
            cursor[i] = run;
            run += v[j];
            if (i == n - 1) rowptr[n] = run;
        }
    }
}

__global__ void scatter_kernel(const void* __restrict__ eiv, const float* __restrict__ ew,
                               int* __restrict__ cursor, int2* __restrict__ edges,
                               const int* __restrict__ flag, int E) {
    int i = blockIdx.x * 256 + threadIdx.x;
    if (i >= E) return;
    int is64 = *flag;
    int r = load_idx(eiv, i, is64);
    int c = load_idx(eiv, (long long)E + i, is64);
    int pos = atomicAdd(&cursor[r], 1);
    edges[pos] = make_int2(c, __float_as_int(ew[i]));
}

// deg from contiguous CSR rows (no atomics); dscale = 0.5 / deg
__global__ void deg_kernel(const int* __restrict__ rowptr, const int2* __restrict__ edges,
                           float* __restrict__ dscale, int n) {
    int i = blockIdx.x * 256 + threadIdx.x;
    if (i >= n) return;
    int s = rowptr[i], e = rowptr[i + 1];
    float d = 0.f;
    for (int j = s; j < e; j++) d += __int_as_float(edges[j].y);
    dscale[i] = 0.5f / fmaxf(d, 1e-12f);
}

// ---------------- weight prep: W[K][OC] -> Wt bf16 [OC][K], pre-swizzled ----------------
__global__ void wprep(const float* __restrict__ W, ushort* __restrict__ Wt, int K, int OC) {
    int c = blockIdx.x;
    int k = threadIdx.x;
    if (k >= K) return;
    int g = k >> 3, j = k & 7;
    Wt[c * K + (((g ^ (c & 7)) << 3) | j)] = f2b(W[k * OC + c]);
}

// ---------------- bf16 MFMA GEMM: C[n,OC] = epi(A[n,K] @ W[K,OC] + b), bf16 out ----------------
// EPI: 0 = relu; 1 = BatchNorm eval then *0.5
template <int K, int OC, int EPI, bool AF32>
__global__ __launch_bounds__(256) void mgemm(const void* __restrict__ A, const ushort* __restrict__ Wt,
                                             const float* __restrict__ bias, ushort* __restrict__ C, int nrows,
                                             const float* __restrict__ bng, const float* __restrict__ bnb,
                                             const float* __restrict__ bnm, const float* __restrict__ bnv) {
    constexpr int GPR = K / 8;             // 16B groups per row
    __shared__ __align__(16) char smem[64 * K * 2 + OC * K * 2];
    char* Al = smem;
    char* Wl = smem + 64 * K * 2;

    const int t = threadIdx.x;
    const int rowbase = blockIdx.x * 64;

    // stage A (reg-staged, XOR-swizzled ds_write_b128)
#pragma unroll
    for (int ch = t; ch < 64 * GPR; ch += 256) {
        int row = ch / GPR, g = ch % GPR;
        int gn = rowbase + row;
        uint4 w = make_uint4(0, 0, 0, 0);
        if (gn < nrows) {
            if (AF32) {
                const float4* p = (const float4*)((const float*)A + (size_t)gn * K + g * 8);
                float4 a0 = p[0], a1 = p[1];
                w.x = pkbf(a0.x, a0.y); w.y = pkbf(a0.z, a0.w);
                w.z = pkbf(a1.x, a1.y); w.w = pkbf(a1.z, a1.w);
            } else {
                w = *(const uint4*)((const ushort*)A + (size_t)gn * K + g * 8);
            }
        }
        *(uint4*)(Al + row * (2 * K) + ((g ^ (row & 7)) << 4)) = w;
    }
    // stage Wt (already pre-swizzled in global) — linear copy
#pragma unroll
    for (int ch = t; ch < OC * GPR; ch += 256) {
        ((uint4*)Wl)[ch] = ((const uint4*)Wt)[ch];
    }
    __syncthreads();

    const int l = t & 63, wv = t >> 6;
    const int lrow = wv * 16 + (l & 15);
    const int lg = l >> 4;

    f32x4 acc[OC / 16];
#pragma unroll
    for (int i = 0; i < OC / 16; i++) acc[i] = (f32x4){0.f, 0.f, 0.f, 0.f};

#pragma unroll
    for (int kk = 0; kk < K / 32; kk++) {
        int ga = kk * 4 + lg;
        short8 af = *(const short8*)(Al + lrow * (2 * K) + ((ga ^ (lrow & 7)) << 4));
#pragma unroll
        for (int ct = 0; ct < OC / 16; ct++) {
            int c = ct * 16 + (l & 15);
            short8 bfr = *(const short8*)(Wl + c * (2 * K) + ((ga ^ (c & 7)) << 4));
            acc[ct] = __builtin_amdgcn_mfma_f32_16x16x32_bf16(af, bfr, acc[ct], 0, 0, 0);
        }
    }

    // epilogue: D row = wv*16 + (l>>4)*4 + r, col = ct*16 + (l&15)
#pragma unroll
    for (int ct = 0; ct < OC / 16; ct++) {
        int c = ct * 16 + (l & 15);
        float bia = bias[c];
        float scale = 0.f, shift = 0.f;
        if (EPI == 1) {
            float rs = rsqrtf(bnv[c] + 1e-5f) * bng[c];
            scale = 0.5f * rs;
            shift = 0.5f * (bnb[c] - bnm[c] * rs);
        }
#pragma unroll
        for (int r = 0; r < 4; r++) {
            int gn = rowbase + wv * 16 + (l >> 4) * 4 + r;
            if (gn < nrows) {
                float v = acc[ct][r] + bia;
                if (EPI == 0) v = fmaxf(v, 0.f);
                else v = v * scale + shift;
                C[(size_t)gn * OC + c] = f2b(v);
            }
        }
    }
}

// ---------------- DEQ step (bf16): zout = dscale[n]*sum(w*zin[col]) + hp[n] ----------------
// 1 wave per node, lane l owns channels (2l, 2l+1)
__global__ __launch_bounds__(256) void deq_step(const uint* __restrict__ zin, uint* __restrict__ zout,
                                                const uint* __restrict__ hp, const float* __restrict__ dscale,
                                                const int* __restrict__ rowptr, const int2* __restrict__ edges) {
    const int n = blockIdx.x * 4 + (threadIdx.x >> 6);
    const int l = threadIdx.x & 63;
    const int s = rowptr[n], e = rowptr[n + 1];
    float ax = 0.f, ay = 0.f;
    int i = s;
    for (; i + 1 < e; i += 2) {
        int2 p0 = edges[i];
        int2 p1 = edges[i + 1];
        uint z0 = zin[(size_t)p0.x * 64 + l];
        uint z1 = zin[(size_t)p1.x * 64 + l];
        float w0 = __int_as_float(p0.y), w1 = __int_as_float(p1.y);
        ax += w0 * blo(z0) + w1 * blo(z1);
        ay += w0 * bhi(z0) + w1 * bhi(z1);
    }
    if (i < e) {
        int2 p = edges[i];
        uint z = zin[(size_t)p.x * 64 + l];
        float w = __int_as_float(p.y);
        ax += w * blo(z);
        ay += w * bhi(z);
    }
    float ds = dscale[n];
    uint hb = hp[(size_t)n * 64 + l];
    zout[(size_t)n * 64 + l] = pkbf(ax * ds + blo(hb), ay * ds + bhi(hb));
}

// ---------------- pool over sorted batch (bf16 input, fp32 atomic out) ----------------
__global__ __launch_bounds__(64) void pool_kernel(const uint* __restrict__ z, const void* __restrict__ batchv,
                                                  const int* __restrict__ flag, float* __restrict__ gpool, int n) {
    const int l = threadIdx.x;
    int n0 = blockIdx.x * 64;
    int n1 = min(n0 + 64, n);
    int is64 = *flag;
    float rx = 0.f, ry = 0.f;
    int cur = -1;
    for (int i = n0; i < n1; i++) {
        int b = load_idx(batchv, i, is64);
        if (b != cur) {
            if (cur >= 0) {
                atomicAdd(&gpool[cur * HD + 2 * l], rx);
                atomicAdd(&gpool[cur * HD + 2 * l + 1], ry);
            }
            rx = 0.f; ry = 0.f;
            cur = b;
        }
        uint zb = z[(size_t)i * 64 + l];
        rx += blo(zb);
        ry += bhi(zb);
    }
    if (cur >= 0) {
        atomicAdd(&gpool[cur * HD + 2 * l], rx);
        atomicAdd(&gpool[cur * HD + 2 * l + 1], ry);
    }
}

// ---------------- graph head: 2x FC + final + log_softmax (fp32) ----------------
__global__ __launch_bounds__(128) void graph_kernel(const float* __restrict__ gpool, const float* __restrict__ gfc_w,
                                                    const float* __restrict__ gfc_b, const float* __restrict__ fw,
                                                    const float* __restrict__ fb, float* __restrict__ out) {
    __shared__ float buf[HD];
    __shared__ float o[10];
    __shared__ float ls;
    const int g = blockIdx.x, t = threadIdx.x;
    buf[t] = gpool[g * HD + t];
    __syncthreads();
    for (int L = 0; L < 2; L++) {
        const float* w = gfc_w + L * HD * HD;
        float s = gfc_b[L * HD + t];
        for (int k = 0; k < HD; k++) s += buf[k] * w[k * HD + t];
        s = fmaxf(s, 0.f);
        __syncthreads();
        buf[t] = s;
        __syncthreads();
    }
    if (t < 10) {
        float s = fb[t];
        for (int k = 0; k < HD; k++) s += buf[k] * fw[k * 10 + t];
        o[t] = s;
    }
    __syncthreads();
    if (t == 0) {
        float m = o[0];
        for (int i = 1; i < 10; i++) m = fmaxf(m, o[i]);
        float se = 0.f;
        for (int i = 0; i < 10; i++) se += expf(o[i] - m);
        ls = m + logf(se);
    }
    __syncthreads();
    if (t < 10) out[g * 10 + t] = o[t] - ls;
}

extern "C" void kernel_launch(void* const* d_in, const int* in_sizes, int n_in,
                              void* d_out, int out_size, void* d_ws, size_t ws_size,
                              hipStream_t stream) {
    const float* x = (const float*)d_in[0];
    const void* eiv = d_in[1];
    const float* ew = (const float*)d_in[2];
    const void* batchv = d_in[3];
    const float* mlp_w1 = (const float*)d_in[4];
    const float* mlp_b1 = (const float*)d_in[5];
    const float* mlp_w2 = (const float*)d_in[6];
    const float* mlp_b2 = (const float*)d_in[7];
    const float* mlp_w3 = (const float*)d_in[8];
    const float* mlp_b3 = (const float*)d_in[9];
    const float* bn_g = (const float*)d_in[10];
    const float* bn_b = (const float*)d_in[11];
    const float* bn_m = (const float*)d_in[12];
    const float* bn_v = (const float*)d_in[13];
    const float* fc_w = (const float*)d_in[14];
    const float* fc_b = (const float*)d_in[15];
    const float* gfc_w = (const float*)d_in[16];
    const float* gfc_b = (const float*)d_in[17];
    const float* fin_w = (const float*)d_in[18];
    const float* fin_b = (const float*)d_in[19];
    float* out = (float*)d_out;

    char* ws = (char*)d_ws;
    size_t off = 0;
    auto alloc = [&](size_t bytes) -> void* {
        void* p = ws + off;
        off = (off + bytes + 255) & ~(size_t)255;
        return p;
    };
    ushort* hpb = (ushort*)alloc((size_t)NN * HD * 2);   // hp bf16
    ushort* za  = (ushort*)alloc((size_t)NN * HD * 2);
    ushort* zb  = (ushort*)alloc((size_t)NN * HD * 2);
    ushort* bfA = (ushort*)alloc((size_t)NN * HD * 2);   // h1 (64c) then h3
    ushort* bfB = (ushort*)alloc((size_t)NN * HD * 2);   // h2 then zfc
    int2* edges = (int2*)alloc((size_t)NE * 8);
    int* rowptr = (int*)alloc((size_t)(NN + 1) * 4);
    int* cursor = (int*)alloc((size_t)NN * 4);
    int* counts = (int*)alloc((size_t)NN * 4);
    float* dscale = (float*)alloc((size_t)NN * 4);
    int* partials = (int*)alloc(1024 * 4);
    float* gpool = (float*)alloc((size_t)NG * HD * 4);
    int* flag = (int*)alloc(256);
    ushort* w1t = (ushort*)alloc(128 * 64 * 2);
    ushort* w2t = (ushort*)alloc(64 * 128 * 2);
    ushort* w3t = (ushort*)alloc(128 * 128 * 2);
    ushort* f1t = (ushort*)alloc(128 * 128 * 2);
    ushort* f2t = (ushort*)alloc(128 * 128 * 2);

    hipMemsetAsync(counts, 0, (size_t)NN * 4, stream);
    hipMemsetAsync(gpool, 0, (size_t)NG * HD * 4, stream);

    detect_kernel<<<1, 64, 0, stream>>>((const unsigned*)eiv, flag);
    count_kernel<<<(NE + 255) / 256, 256, 0, stream>>>(eiv, counts, flag, NE);
    const int NB = (NN + 1023) / 1024;
    scan_pass1<<<NB, 256, 0, stream>>>(counts, partials, NN);
    scan_pass2<<<1, 64, 0, stream>>>(partials, NB);
    scan_pass3<<<NB, 256, 0, stream>>>(counts, partials, rowptr, cursor, NN);
    scatter_kernel<<<(NE + 255) / 256, 256, 0, stream>>>(eiv, ew, cursor, edges, flag, NE);
    deg_kernel<<<(NN + 255) / 256, 256, 0, stream>>>(rowptr, edges, dscale, NN);

    // weight prep (bf16, transposed, pre-swizzled)
    wprep<<<64, 128, 0, stream>>>(mlp_w1, w1t, 128, 64);
    wprep<<<128, 64, 0, stream>>>(mlp_w2, w2t, 64, 128);
    wprep<<<128, 128, 0, stream>>>(mlp_w3, w3t, 128, 128);
    wprep<<<128, 128, 0, stream>>>(fc_w, f1t, 128, 128);
    wprep<<<128, 128, 0, stream>>>(fc_w + 128 * 128, f2t, 128, 128);

    const int GB = (NN + 63) / 64;
    // MLP encoder: x -> relu -> relu -> BN*0.5 = hp
    mgemm<128, 64, 0, true><<<GB, 256, 0, stream>>>(x, w1t, mlp_b1, bfA, NN, nullptr, nullptr, nullptr, nullptr);
    mgemm<64, 128, 0, false><<<GB, 256, 0, stream>>>(bfA, w2t, mlp_b2, bfB, NN, nullptr, nullptr, nullptr, nullptr);
    mgemm<128, 128, 1, false><<<GB, 256, 0, stream>>>(bfB, w3t, mlp_b3, hpb, NN, bn_g, bn_b, bn_m, bn_v);

    // DEQ: z1 = hp (analytic), then 9 propagation steps
    const uint* zin = (const uint*)hpb;
    uint* zbufs[2] = {(uint*)za, (uint*)zb};
    for (int it = 0; it < 9; it++) {
        uint* zout = zbufs[it & 1];
        deq_step<<<NN / 4, 256, 0, stream>>>(zin, zout, (const uint*)hpb, dscale, rowptr, edges);
        zin = zout;
    }
    // zin == za after 9 steps

    // node FC stack
    mgemm<128, 128, 0, false><<<GB, 256, 0, stream>>>(za, f1t, fc_b, bfA, NN, nullptr, nullptr, nullptr, nullptr);
    mgemm<128, 128, 0, false><<<GB, 256, 0, stream>>>(bfA, f2t, fc_b + 128, bfB, NN, nullptr, nullptr, nullptr, nullptr);

    pool_kernel<<<(NN + 63) / 64, 64, 0, stream>>>((const uint*)bfB, batchv, flag, gpool, NN);
    graph_kernel<<<NG, 128, 0, stream>>>(gpool, gfc_w, gfc_b, fin_w, fin_b, out);
}

// Round 3
// 1105.335 us; speedup vs baseline: 1.7864x; 1.1652x over previous
//
#include <hip/hip_runtime.h>

#define NN 100000
#define NE 1600000
#define NG 512
#define HD 128
#define NBUK 782   // (NN+127)>>7, 128 rows per bucket

typedef short short8 __attribute__((ext_vector_type(8)));
typedef float f32x4 __attribute__((ext_vector_type(4)));

__device__ __forceinline__ ushort f2b(float v) {
    uint u = __float_as_uint(v);
    u = (u + 0x7fffu + ((u >> 16) & 1u)) >> 16;
    return (ushort)u;
}
__device__ __forceinline__ uint pkbf(float a, float b) {
    return (uint)f2b(a) | ((uint)f2b(b) << 16);
}
__device__ __forceinline__ float blo(uint u) { return __uint_as_float(u << 16); }
__device__ __forceinline__ float bhi(uint u) { return __uint_as_float(u & 0xffff0000u); }

// ---------------- dtype detect: int64 vs int32 edge_index ----------------
__global__ void detect_kernel(const unsigned* __restrict__ ei, int* __restrict__ flag) {
    unsigned v = ei[threadIdx.x * 2 + 1];
    unsigned long long m = __ballot(v != 0u);
    if (threadIdx.x == 0) flag[0] = (m == 0ull) ? 1 : 0;
}

__device__ __forceinline__ int load_idx(const void* p, long long i, int is64) {
    return is64 ? (int)((const long long*)p)[i] : ((const int*)p)[i];
}

// ---------------- bucketed CSR build (atomic-light) ----------------
// Phase A: bucket histogram (LDS) -> global bucket counts
__global__ __launch_bounds__(256) void bkt_count(const void* __restrict__ eiv, const int* __restrict__ flag,
                                                 int* __restrict__ bcnt, int E) {
    __shared__ int h[NBUK];
    for (int i = threadIdx.x; i < NBUK; i += 256) h[i] = 0;
    __syncthreads();
    int is64 = *flag;
    int stride = gridDim.x * 256;
    for (int i = blockIdx.x * 256 + threadIdx.x; i < E; i += stride) {
        int r = load_idx(eiv, i, is64);
        atomicAdd(&h[r >> 7], 1);
    }
    __syncthreads();
    for (int i = threadIdx.x; i < NBUK; i += 256) {
        int v = h[i];
        if (v) atomicAdd(&bcnt[i], v);
    }
}

// Phase B: scan bucket counts -> bucket_start[NBUK+1], bucket_cur
__global__ __launch_bounds__(1024) void bucket_scan(const int* __restrict__ bcnt, int* __restrict__ bstart,
                                                    int* __restrict__ bcur) {
    __shared__ int s[1024];
    int t = threadIdx.x;
    int own = (t < NBUK) ? bcnt[t] : 0;
    s[t] = own;
    __syncthreads();
    for (int off = 1; off < 1024; off <<= 1) {
        int v = (t >= off) ? s[t - off] : 0;
        __syncthreads();
        s[t] += v;
        __syncthreads();
    }
    if (t < NBUK) {
        int excl = s[t] - own;
        bstart[t] = excl;
        bcur[t] = excl;
    }
    if (t == NBUK - 1) bstart[NBUK] = s[t];
}

// Phase C: scatter edges into bucket regions (chunk reservation, LDS cursors)
__global__ __launch_bounds__(256) void bkt_scatter(const void* __restrict__ eiv, const float* __restrict__ ew,
                                                   const int* __restrict__ flag, int* __restrict__ bcur,
                                                   unsigned char* __restrict__ brow, int2* __restrict__ bcw, int E) {
    __shared__ int h[NBUK];
    __shared__ int c[NBUK];
    for (int i = threadIdx.x; i < NBUK; i += 256) { h[i] = 0; c[i] = 0; }
    __syncthreads();
    int is64 = *flag;
    int per = (E + gridDim.x - 1) / gridDim.x;
    int e0 = blockIdx.x * per, e1 = min(e0 + per, E);
    for (int i = e0 + threadIdx.x; i < e1; i += 256) {
        int r = load_idx(eiv, i, is64);
        atomicAdd(&h[r >> 7], 1);
    }
    __syncthreads();
    for (int i = threadIdx.x; i < NBUK; i += 256) {
        int v = h[i];
        h[i] = v ? atomicAdd(&bcur[i], v) : 0;
    }
    __syncthreads();
    for (int i = e0 + threadIdx.x; i < e1; i += 256) {
        int r = load_idx(eiv, i, is64);
        int col = load_idx(eiv, (long long)E + i, is64);
        int b = r >> 7;
        int pos = h[b] + atomicAdd(&c[b], 1);
        brow[pos] = (unsigned char)(r & 127);
        bcw[pos] = make_int2(col, __float_as_int(ew[i]));
    }
}

// Phase D: per-bucket finalize: row hist, scan -> rowptr, scatter to CSR, deg -> dscale
__global__ __launch_bounds__(256) void bkt_finalize(const int* __restrict__ bstart, const unsigned char* __restrict__ brow,
                                                    const int2* __restrict__ bcw, int* __restrict__ rowptr,
                                                    int2* __restrict__ edges, float* __restrict__ dscale, int E) {
    __shared__ int rh[128];
    __shared__ int rb[128];
    __shared__ int rc[128];
    __shared__ float wsum[128];
    int b = blockIdx.x;
    int t = threadIdx.x;
    if (t < 128) { rh[t] = 0; rc[t] = 0; wsum[t] = 0.f; }
    __syncthreads();
    int s0 = bstart[b], s1 = bstart[b + 1];
    for (int j = s0 + t; j < s1; j += 256) atomicAdd(&rh[brow[j]], 1);
    __syncthreads();
    if (t < 128) rb[t] = rh[t];
    __syncthreads();
    for (int off = 1; off < 128; off <<= 1) {
        int v = 0;
        if (t < 128 && t >= off) v = rb[t - off];
        __syncthreads();
        if (t < 128) rb[t] += v;
        __syncthreads();
    }
    int rows = min(128, NN - b * 128);
    if (t < rows) rowptr[b * 128 + t] = s0 + rb[t] - rh[t];
    if (b == NBUK - 1 && t == 0) rowptr[NN] = E;
    __syncthreads();
    for (int j = s0 + t; j < s1; j += 256) {
        int2 cw = bcw[j];
        int r = brow[j];
        int pos = s0 + rb[r] - rh[r] + atomicAdd(&rc[r], 1);
        edges[pos] = cw;
        atomicAdd(&wsum[r], __int_as_float(cw.y));
    }
    __syncthreads();
    if (t < rows) dscale[b * 128 + t] = 0.5f / fmaxf(wsum[t], 1e-12f);
}

// ---------------- weight prep: W[K][OC] -> Wt bf16 [OC][K], pre-swizzled ----------------
__global__ void wprep(const float* __restrict__ W, ushort* __restrict__ Wt, int K, int OC) {
    int c = blockIdx.x;
    int k = threadIdx.x;
    if (k >= K) return;
    int g = k >> 3, j = k & 7;
    Wt[c * K + (((g ^ (c & 7)) << 3) | j)] = f2b(W[k * OC + c]);
}

// ---------------- bf16 MFMA GEMM: C[n,OC] = epi(A[n,K] @ W[K,OC] + b), bf16 out ----------------
template <int K, int OC, int EPI, bool AF32>
__global__ __launch_bounds__(256) void mgemm(const void* __restrict__ A, const ushort* __restrict__ Wt,
                                             const float* __restrict__ bias, ushort* __restrict__ C, int nrows,
                                             const float* __restrict__ bng, const float* __restrict__ bnb,
                                             const float* __restrict__ bnm, const float* __restrict__ bnv) {
    constexpr int GPR = K / 8;
    __shared__ __align__(16) char smem[64 * K * 2 + OC * K * 2];
    char* Al = smem;
    char* Wl = smem + 64 * K * 2;

    const int t = threadIdx.x;
    const int rowbase = blockIdx.x * 64;

#pragma unroll
    for (int ch = t; ch < 64 * GPR; ch += 256) {
        int row = ch / GPR, g = ch % GPR;
        int gn = rowbase + row;
        uint4 w = make_uint4(0, 0, 0, 0);
        if (gn < nrows) {
            if (AF32) {
                const float4* p = (const float4*)((const float*)A + (size_t)gn * K + g * 8);
                float4 a0 = p[0], a1 = p[1];
                w.x = pkbf(a0.x, a0.y); w.y = pkbf(a0.z, a0.w);
                w.z = pkbf(a1.x, a1.y); w.w = pkbf(a1.z, a1.w);
            } else {
                w = *(const uint4*)((const ushort*)A + (size_t)gn * K + g * 8);
            }
        }
        *(uint4*)(Al + row * (2 * K) + ((g ^ (row & 7)) << 4)) = w;
    }
#pragma unroll
    for (int ch = t; ch < OC * GPR; ch += 256) {
        ((uint4*)Wl)[ch] = ((const uint4*)Wt)[ch];
    }
    __syncthreads();

    const int l = t & 63, wv = t >> 6;
    const int lrow = wv * 16 + (l & 15);
    const int lg = l >> 4;

    f32x4 acc[OC / 16];
#pragma unroll
    for (int i = 0; i < OC / 16; i++) acc[i] = (f32x4){0.f, 0.f, 0.f, 0.f};

#pragma unroll
    for (int kk = 0; kk < K / 32; kk++) {
        int ga = kk * 4 + lg;
        short8 af = *(const short8*)(Al + lrow * (2 * K) + ((ga ^ (lrow & 7)) << 4));
#pragma unroll
        for (int ct = 0; ct < OC / 16; ct++) {
            int c = ct * 16 + (l & 15);
            short8 bfr = *(const short8*)(Wl + c * (2 * K) + ((ga ^ (c & 7)) << 4));
            acc[ct] = __builtin_amdgcn_mfma_f32_16x16x32_bf16(af, bfr, acc[ct], 0, 0, 0);
        }
    }

#pragma unroll
    for (int ct = 0; ct < OC / 16; ct++) {
        int c = ct * 16 + (l & 15);
        float bia = bias[c];
        float scale = 0.f, shift = 0.f;
        if (EPI == 1) {
            float rs = rsqrtf(bnv[c] + 1e-5f) * bng[c];
            scale = 0.5f * rs;
            shift = 0.5f * (bnb[c] - bnm[c] * rs);
        }
#pragma unroll
        for (int r = 0; r < 4; r++) {
            int gn = rowbase + wv * 16 + (l >> 4) * 4 + r;
            if (gn < nrows) {
                float v = acc[ct][r] + bia;
                if (EPI == 0) v = fmaxf(v, 0.f);
                else v = v * scale + shift;
                C[(size_t)gn * OC + c] = f2b(v);
            }
        }
    }
}

// ---------------- DEQ step: zout = dscale[n]*sum(w*zin[col]) + hp[n] ----------------
// formats: 0 = bf16 (uint per lane), 1 = fp8 e4m3 (ushort per lane); lane l owns ch (2l, 2l+1)
template <int INF, int OUTF>
__global__ __launch_bounds__(256) void deq_step(const void* __restrict__ zin, void* __restrict__ zout,
                                                const uint* __restrict__ hp, const float* __restrict__ dscale,
                                                const int* __restrict__ rowptr, const int2* __restrict__ edges) {
    const int n = blockIdx.x * 4 + (threadIdx.x >> 6);
    const int l = threadIdx.x & 63;
    const int s = rowptr[n], e = rowptr[n + 1];
    float ax = 0.f, ay = 0.f;
    int i = s;
    for (; i + 1 < e; i += 2) {
        int2 p0 = edges[i];
        int2 p1 = edges[i + 1];
        float w0 = __int_as_float(p0.y), w1 = __int_as_float(p1.y);
        if (INF == 0) {
            uint z0 = ((const uint*)zin)[(size_t)p0.x * 64 + l];
            uint z1 = ((const uint*)zin)[(size_t)p1.x * 64 + l];
            ax += w0 * blo(z0) + w1 * blo(z1);
            ay += w0 * bhi(z0) + w1 * bhi(z1);
        } else {
            uint v0 = ((const ushort*)zin)[(size_t)p0.x * 64 + l];
            uint v1 = ((const ushort*)zin)[(size_t)p1.x * 64 + l];
            auto f0 = __builtin_amdgcn_cvt_pk_f32_fp8((int)v0, false);
            auto f1 = __builtin_amdgcn_cvt_pk_f32_fp8((int)v1, false);
            ax += w0 * f0[0] + w1 * f1[0];
            ay += w0 * f0[1] + w1 * f1[1];
        }
    }
    if (i < e) {
        int2 p = edges[i];
        float w = __int_as_float(p.y);
        if (INF == 0) {
            uint z = ((const uint*)zin)[(size_t)p.x * 64 + l];
            ax += w * blo(z);
            ay += w * bhi(z);
        } else {
            uint v = ((const ushort*)zin)[(size_t)p.x * 64 + l];
            auto f = __builtin_amdgcn_cvt_pk_f32_fp8((int)v, false);
            ax += w * f[0];
            ay += w * f[1];
        }
    }
    float ds = dscale[n];
    uint hb = hp[(size_t)n * 64 + l];
    float ox = ax * ds + blo(hb);
    float oy = ay * ds + bhi(hb);
    if (OUTF == 0) {
        ((uint*)zout)[(size_t)n * 64 + l] = pkbf(ox, oy);
    } else {
        int pk = __builtin_amdgcn_cvt_pk_fp8_f32(ox, oy, 0, false);
        ((ushort*)zout)[(size_t)n * 64 + l] = (ushort)pk;
    }
}

// ---------------- pool over sorted batch (bf16 input, fp32 atomic out) ----------------
__global__ __launch_bounds__(64) void pool_kernel(const uint* __restrict__ z, const void* __restrict__ batchv,
                                                  const int* __restrict__ flag, float* __restrict__ gpool, int n) {
    const int l = threadIdx.x;
    int n0 = blockIdx.x * 64;
    int n1 = min(n0 + 64, n);
    int is64 = *flag;
    float rx = 0.f, ry = 0.f;
    int cur = -1;
    for (int i = n0; i < n1; i++) {
        int b = load_idx(batchv, i, is64);
        if (b != cur) {
            if (cur >= 0) {
                atomicAdd(&gpool[cur * HD + 2 * l], rx);
                atomicAdd(&gpool[cur * HD + 2 * l + 1], ry);
            }
            rx = 0.f; ry = 0.f;
            cur = b;
        }
        uint zb = z[(size_t)i * 64 + l];
        rx += blo(zb);
        ry += bhi(zb);
    }
    if (cur >= 0) {
        atomicAdd(&gpool[cur * HD + 2 * l], rx);
        atomicAdd(&gpool[cur * HD + 2 * l + 1], ry);
    }
}

// ---------------- graph head: 2x FC + final + log_softmax (fp32) ----------------
__global__ __launch_bounds__(128) void graph_kernel(const float* __restrict__ gpool, const float* __restrict__ gfc_w,
                                                    const float* __restrict__ gfc_b, const float* __restrict__ fw,
                                                    const float* __restrict__ fb, float* __restrict__ out) {
    __shared__ float buf[HD];
    __shared__ float o[10];
    __shared__ float ls;
    const int g = blockIdx.x, t = threadIdx.x;
    buf[t] = gpool[g * HD + t];
    __syncthreads();
    for (int L = 0; L < 2; L++) {
        const float* w = gfc_w + L * HD * HD;
        float s = gfc_b[L * HD + t];
        for (int k = 0; k < HD; k++) s += buf[k] * w[k * HD + t];
        s = fmaxf(s, 0.f);
        __syncthreads();
        buf[t] = s;
        __syncthreads();
    }
    if (t < 10) {
        float s = fb[t];
        for (int k = 0; k < HD; k++) s += buf[k] * fw[k * 10 + t];
        o[t] = s;
    }
    __syncthreads();
    if (t == 0) {
        float m = o[0];
        for (int i = 1; i < 10; i++) m = fmaxf(m, o[i]);
        float se = 0.f;
        for (int i = 0; i < 10; i++) se += expf(o[i] - m);
        ls = m + logf(se);
    }
    __syncthreads();
    if (t < 10) out[g * 10 + t] = o[t] - ls;
}

extern "C" void kernel_launch(void* const* d_in, const int* in_sizes, int n_in,
                              void* d_out, int out_size, void* d_ws, size_t ws_size,
                              hipStream_t stream) {
    const float* x = (const float*)d_in[0];
    const void* eiv = d_in[1];
    const float* ew = (const float*)d_in[2];
    const void* batchv = d_in[3];
    const float* mlp_w1 = (const float*)d_in[4];
    const float* mlp_b1 = (const float*)d_in[5];
    const float* mlp_w2 = (const float*)d_in[6];
    const float* mlp_b2 = (const float*)d_in[7];
    const float* mlp_w3 = (const float*)d_in[8];
    const float* mlp_b3 = (const float*)d_in[9];
    const float* bn_g = (const float*)d_in[10];
    const float* bn_b = (const float*)d_in[11];
    const float* bn_m = (const float*)d_in[12];
    const float* bn_v = (const float*)d_in[13];
    const float* fc_w = (const float*)d_in[14];
    const float* fc_b = (const float*)d_in[15];
    const float* gfc_w = (const float*)d_in[16];
    const float* gfc_b = (const float*)d_in[17];
    const float* fin_w = (const float*)d_in[18];
    const float* fin_b = (const float*)d_in[19];
    float* out = (float*)d_out;

    char* ws = (char*)d_ws;
    size_t off = 0;
    auto alloc = [&](size_t bytes) -> void* {
        void* p = ws + off;
        off = (off + bytes + 255) & ~(size_t)255;
        return p;
    };
    // persistent-through-deq
    ushort* hpb = (ushort*)alloc((size_t)NN * HD * 2);        // hp bf16 (25.6MB)
    ushort* za  = (ushort*)alloc((size_t)NN * HD * 2);        // final z bf16 (25.6MB)
    int2* edges = (int2*)alloc((size_t)NE * 8);               // CSR edges (12.8MB)
    // region1: fp8 z double buffer (12.8+12.8) ∪ bfA (25.6)
    char* region1 = (char*)alloc((size_t)NN * HD * 2);
    ushort* zf8a = (ushort*)region1;                          // fp8 pair per lane
    ushort* zf8b = (ushort*)(region1 + (size_t)NN * HD);
    ushort* bfA = (ushort*)region1;
    // region2: brow(1.6)+bcw(12.8) ∪ bfB (25.6)
    char* region2 = (char*)alloc((size_t)NN * HD * 2);
    unsigned char* brow = (unsigned char*)region2;
    int2* bcw = (int2*)(region2 + ((size_t)NE + 256));
    ushort* bfB = (ushort*)region2;
    // small stuff
    int* rowptr = (int*)alloc((size_t)(NN + 1) * 4);
    float* dscale = (float*)alloc((size_t)NN * 4);
    int* bcnt = (int*)alloc((size_t)NBUK * 4);
    int* bstart = (int*)alloc((size_t)(NBUK + 1) * 4);
    int* bcur = (int*)alloc((size_t)NBUK * 4);
    float* gpool = (float*)alloc((size_t)NG * HD * 4);
    int* flag = (int*)alloc(256);
    ushort* w1t = (ushort*)alloc(128 * 64 * 2);
    ushort* w2t = (ushort*)alloc(64 * 128 * 2);
    ushort* w3t = (ushort*)alloc(128 * 128 * 2);
    ushort* f1t = (ushort*)alloc(128 * 128 * 2);
    ushort* f2t = (ushort*)alloc(128 * 128 * 2);

    hipMemsetAsync(bcnt, 0, (size_t)NBUK * 4, stream);
    hipMemsetAsync(gpool, 0, (size_t)NG * HD * 4, stream);

    detect_kernel<<<1, 64, 0, stream>>>((const unsigned*)eiv, flag);
    // CSR build (bucketed, atomic-light)
    bkt_count<<<256, 256, 0, stream>>>(eiv, flag, bcnt, NE);
    bucket_scan<<<1, 1024, 0, stream>>>(bcnt, bstart, bcur);
    bkt_scatter<<<256, 256, 0, stream>>>(eiv, ew, flag, bcur, brow, bcw, NE);
    bkt_finalize<<<NBUK, 256, 0, stream>>>(bstart, brow, bcw, rowptr, edges, dscale, NE);

    // weight prep (bf16, transposed, pre-swizzled)
    wprep<<<64, 128, 0, stream>>>(mlp_w1, w1t, 128, 64);
    wprep<<<128, 64, 0, stream>>>(mlp_w2, w2t, 64, 128);
    wprep<<<128, 128, 0, stream>>>(mlp_w3, w3t, 128, 128);
    wprep<<<128, 128, 0, stream>>>(fc_w, f1t, 128, 128);
    wprep<<<128, 128, 0, stream>>>(fc_w + 128 * 128, f2t, 128, 128);

    const int GB = (NN + 63) / 64;
    // MLP encoder: x -> relu -> relu -> BN*0.5 = hp   (bfA=region1, bfB=region2: CSR temps already consumed)
    mgemm<128, 64, 0, true><<<GB, 256, 0, stream>>>(x, w1t, mlp_b1, bfA, NN, nullptr, nullptr, nullptr, nullptr);
    mgemm<64, 128, 0, false><<<GB, 256, 0, stream>>>(bfA, w2t, mlp_b2, bfB, NN, nullptr, nullptr, nullptr, nullptr);
    mgemm<128, 128, 1, false><<<GB, 256, 0, stream>>>(bfB, w3t, mlp_b3, hpb, NN, bn_g, bn_b, bn_m, bn_v);

    // DEQ: z1 = hp (analytic). 9 propagation steps: bf16->fp8, fp8->fp8 x7, fp8->bf16
    deq_step<0, 1><<<NN / 4, 256, 0, stream>>>(hpb, zf8a, (const uint*)hpb, dscale, rowptr, edges);
    {
        ushort* bufs[2] = {zf8a, zf8b};
        for (int it = 1; it <= 7; it++) {
            deq_step<1, 1><<<NN / 4, 256, 0, stream>>>(bufs[(it + 1) & 1], bufs[it & 1], (const uint*)hpb,
                                                       dscale, rowptr, edges);
        }
    }
    deq_step<1, 0><<<NN / 4, 256, 0, stream>>>(zf8b, za, (const uint*)hpb, dscale, rowptr, edges);

    // node FC stack (bfA overwrites dead fp8 buffers; bfB overwrites dead bcw/brow)
    mgemm<128, 128, 0, false><<<GB, 256, 0, stream>>>(za, f1t, fc_b, bfA, NN, nullptr, nullptr, nullptr, nullptr);
    mgemm<128, 128, 0, false><<<GB, 256, 0, stream>>>(bfA, f2t, fc_b + 128, bfB, NN, nullptr, nullptr, nullptr, nullptr);

    pool_kernel<<<(NN + 63) / 64, 64, 0, stream>>>((const uint*)bfB, batchv, flag, gpool, NN);
    graph_kernel<<<NG, 128, 0, stream>>>(gpool, gfc_w, gfc_b, fin_w, fin_b, out);
}

// Round 4
// 873.340 us; speedup vs baseline: 2.2610x; 1.2656x over previous
//
#include <hip/hip_runtime.h>

#define NN 100000
#define NE 1600000
#define NG 512
#define HD 128
#define NBUK 782   // (NN+127)>>7, 128 rows per bucket

typedef short short8 __attribute__((ext_vector_type(8)));
typedef float f32x4 __attribute__((ext_vector_type(4)));

__device__ __forceinline__ ushort f2b(float v) {
    uint u = __float_as_uint(v);
    u = (u + 0x7fffu + ((u >> 16) & 1u)) >> 16;
    return (ushort)u;
}
__device__ __forceinline__ uint pkbf(float a, float b) {
    return (uint)f2b(a) | ((uint)f2b(b) << 16);
}
__device__ __forceinline__ float blo(uint u) { return __uint_as_float(u << 16); }
__device__ __forceinline__ float bhi(uint u) { return __uint_as_float(u & 0xffff0000u); }

// ---------------- dtype detect: int64 vs int32 edge_index ----------------
__global__ void detect_kernel(const unsigned* __restrict__ ei, int* __restrict__ flag) {
    unsigned v = ei[threadIdx.x * 2 + 1];
    unsigned long long m = __ballot(v != 0u);
    if (threadIdx.x == 0) flag[0] = (m == 0ull) ? 1 : 0;
}

__device__ __forceinline__ int load_idx(const void* p, long long i, int is64) {
    return is64 ? (int)((const long long*)p)[i] : ((const int*)p)[i];
}

// ---------------- bucketed CSR build (atomic-light) ----------------
__global__ __launch_bounds__(256) void bkt_count(const void* __restrict__ eiv, const int* __restrict__ flag,
                                                 int* __restrict__ bcnt, int E) {
    __shared__ int h[NBUK];
    for (int i = threadIdx.x; i < NBUK; i += 256) h[i] = 0;
    __syncthreads();
    int is64 = *flag;
    int stride = gridDim.x * 256;
    for (int i = blockIdx.x * 256 + threadIdx.x; i < E; i += stride) {
        int r = load_idx(eiv, i, is64);
        atomicAdd(&h[r >> 7], 1);
    }
    __syncthreads();
    for (int i = threadIdx.x; i < NBUK; i += 256) {
        int v = h[i];
        if (v) atomicAdd(&bcnt[i], v);
    }
}

__global__ __launch_bounds__(1024) void bucket_scan(const int* __restrict__ bcnt, int* __restrict__ bstart,
                                                    int* __restrict__ bcur) {
    __shared__ int s[1024];
    int t = threadIdx.x;
    int own = (t < NBUK) ? bcnt[t] : 0;
    s[t] = own;
    __syncthreads();
    for (int off = 1; off < 1024; off <<= 1) {
        int v = (t >= off) ? s[t - off] : 0;
        __syncthreads();
        s[t] += v;
        __syncthreads();
    }
    if (t < NBUK) {
        int excl = s[t] - own;
        bstart[t] = excl;
        bcur[t] = excl;
    }
    if (t == NBUK - 1) bstart[NBUK] = s[t];
}

__global__ __launch_bounds__(256) void bkt_scatter(const void* __restrict__ eiv, const float* __restrict__ ew,
                                                   const int* __restrict__ flag, int* __restrict__ bcur,
                                                   unsigned char* __restrict__ brow, int2* __restrict__ bcw, int E) {
    __shared__ int h[NBUK];
    __shared__ int c[NBUK];
    for (int i = threadIdx.x; i < NBUK; i += 256) { h[i] = 0; c[i] = 0; }
    __syncthreads();
    int is64 = *flag;
    int per = (E + gridDim.x - 1) / gridDim.x;
    int e0 = blockIdx.x * per, e1 = min(e0 + per, E);
    for (int i = e0 + threadIdx.x; i < e1; i += 256) {
        int r = load_idx(eiv, i, is64);
        atomicAdd(&h[r >> 7], 1);
    }
    __syncthreads();
    for (int i = threadIdx.x; i < NBUK; i += 256) {
        int v = h[i];
        h[i] = v ? atomicAdd(&bcur[i], v) : 0;
    }
    __syncthreads();
    for (int i = e0 + threadIdx.x; i < e1; i += 256) {
        int r = load_idx(eiv, i, is64);
        int col = load_idx(eiv, (long long)E + i, is64);
        int b = r >> 7;
        int pos = h[b] + atomicAdd(&c[b], 1);
        brow[pos] = (unsigned char)(r & 127);
        bcw[pos] = make_int2(col, __float_as_int(ew[i]));
    }
}

__global__ __launch_bounds__(256) void bkt_finalize(const int* __restrict__ bstart, const unsigned char* __restrict__ brow,
                                                    const int2* __restrict__ bcw, int* __restrict__ rowptr,
                                                    int2* __restrict__ edges, float* __restrict__ dscale, int E) {
    __shared__ int rh[128];
    __shared__ int rb[128];
    __shared__ int rc[128];
    __shared__ float wsum[128];
    int b = blockIdx.x;
    int t = threadIdx.x;
    if (t < 128) { rh[t] = 0; rc[t] = 0; wsum[t] = 0.f; }
    __syncthreads();
    int s0 = bstart[b], s1 = bstart[b + 1];
    for (int j = s0 + t; j < s1; j += 256) atomicAdd(&rh[brow[j]], 1);
    __syncthreads();
    if (t < 128) rb[t] = rh[t];
    __syncthreads();
    for (int off = 1; off < 128; off <<= 1) {
        int v = 0;
        if (t < 128 && t >= off) v = rb[t - off];
        __syncthreads();
        if (t < 128) rb[t] += v;
        __syncthreads();
    }
    int rows = min(128, NN - b * 128);
    if (t < rows) rowptr[b * 128 + t] = s0 + rb[t] - rh[t];
    if (b == NBUK - 1 && t == 0) rowptr[NN] = E;
    __syncthreads();
    for (int j = s0 + t; j < s1; j += 256) {
        int2 cw = bcw[j];
        int r = brow[j];
        int pos = s0 + rb[r] - rh[r] + atomicAdd(&rc[r], 1);
        edges[pos] = cw;
        atomicAdd(&wsum[r], __int_as_float(cw.y));
    }
    __syncthreads();
    if (t < rows) dscale[b * 128 + t] = 0.5f / fmaxf(wsum[t], 1e-12f);
}

// ---------------- weight prep: W[K][OC] -> Wt bf16 [OC][K], pre-swizzled ----------------
__global__ void wprep(const float* __restrict__ W, ushort* __restrict__ Wt, int K, int OC) {
    int c = blockIdx.x;
    int k = threadIdx.x;
    if (k >= K) return;
    int g = k >> 3, j = k & 7;
    Wt[c * K + (((g ^ (c & 7)) << 3) | j)] = f2b(W[k * OC + c]);
}

// ---------------- bf16 MFMA GEMM: C[n,OC] = epi(A[n,K] @ W[K,OC] + b), bf16 out ----------------
template <int K, int OC, int EPI, bool AF32>
__global__ __launch_bounds__(256) void mgemm(const void* __restrict__ A, const ushort* __restrict__ Wt,
                                             const float* __restrict__ bias, ushort* __restrict__ C, int nrows,
                                             const float* __restrict__ bng, const float* __restrict__ bnb,
                                             const float* __restrict__ bnm, const float* __restrict__ bnv) {
    constexpr int GPR = K / 8;
    __shared__ __align__(16) char smem[64 * K * 2 + OC * K * 2];
    char* Al = smem;
    char* Wl = smem + 64 * K * 2;

    const int t = threadIdx.x;
    const int rowbase = blockIdx.x * 64;

#pragma unroll
    for (int ch = t; ch < 64 * GPR; ch += 256) {
        int row = ch / GPR, g = ch % GPR;
        int gn = rowbase + row;
        uint4 w = make_uint4(0, 0, 0, 0);
        if (gn < nrows) {
            if (AF32) {
                const float4* p = (const float4*)((const float*)A + (size_t)gn * K + g * 8);
                float4 a0 = p[0], a1 = p[1];
                w.x = pkbf(a0.x, a0.y); w.y = pkbf(a0.z, a0.w);
                w.z = pkbf(a1.x, a1.y); w.w = pkbf(a1.z, a1.w);
            } else {
                w = *(const uint4*)((const ushort*)A + (size_t)gn * K + g * 8);
            }
        }
        *(uint4*)(Al + row * (2 * K) + ((g ^ (row & 7)) << 4)) = w;
    }
#pragma unroll
    for (int ch = t; ch < OC * GPR; ch += 256) {
        ((uint4*)Wl)[ch] = ((const uint4*)Wt)[ch];
    }
    __syncthreads();

    const int l = t & 63, wv = t >> 6;
    const int lrow = wv * 16 + (l & 15);
    const int lg = l >> 4;

    f32x4 acc[OC / 16];
#pragma unroll
    for (int i = 0; i < OC / 16; i++) acc[i] = (f32x4){0.f, 0.f, 0.f, 0.f};

#pragma unroll
    for (int kk = 0; kk < K / 32; kk++) {
        int ga = kk * 4 + lg;
        short8 af = *(const short8*)(Al + lrow * (2 * K) + ((ga ^ (lrow & 7)) << 4));
#pragma unroll
        for (int ct = 0; ct < OC / 16; ct++) {
            int c = ct * 16 + (l & 15);
            short8 bfr = *(const short8*)(Wl + c * (2 * K) + ((ga ^ (c & 7)) << 4));
            acc[ct] = __builtin_amdgcn_mfma_f32_16x16x32_bf16(af, bfr, acc[ct], 0, 0, 0);
        }
    }

#pragma unroll
    for (int ct = 0; ct < OC / 16; ct++) {
        int c = ct * 16 + (l & 15);
        float bia = bias[c];
        float scale = 0.f, shift = 0.f;
        if (EPI == 1) {
            float rs = rsqrtf(bnv[c] + 1e-5f) * bng[c];
            scale = 0.5f * rs;
            shift = 0.5f * (bnb[c] - bnm[c] * rs);
        }
#pragma unroll
        for (int r = 0; r < 4; r++) {
            int gn = rowbase + wv * 16 + (l >> 4) * 4 + r;
            if (gn < nrows) {
                float v = acc[ct][r] + bia;
                if (EPI == 0) v = fmaxf(v, 0.f);
                else v = v * scale + shift;
                C[(size_t)gn * OC + c] = f2b(v);
            }
        }
    }
}

// ---------------- DEQ step: zout = dscale[n]*sum(w*zin[col]) + hp[n] ----------------
// Quarter-wave decomposition: 16 lanes per node, 4 nodes/wave, lane owns 8 channels.
// One gather instruction covers 4 z-rows (4x MLP); inner loop unrolled x2 (8 rows in flight).
// formats: 0 = bf16, 1 = fp8 e4m3
template <int INF, int OUTF>
__global__ __launch_bounds__(256) void deq_step(const void* __restrict__ zin, void* __restrict__ zout,
                                                const uint* __restrict__ hp, const float* __restrict__ dscale,
                                                const int* __restrict__ rowptr,
                                                const long long* __restrict__ edges) {
    const int n = blockIdx.x * 16 + (threadIdx.x >> 4);
    const int lq = threadIdx.x & 15;
    const int s = rowptr[n], e = rowptr[n + 1];
    float a0 = 0.f, a1 = 0.f, a2 = 0.f, a3 = 0.f, a4 = 0.f, a5 = 0.f, a6 = 0.f, a7 = 0.f;

    for (int i = s; i < e; i += 2) {
        long long e0 = __builtin_nontemporal_load(&edges[i]);
        bool has1 = (i + 1 < e);
        long long e1 = __builtin_nontemporal_load(&edges[has1 ? i + 1 : i]);
        int c0 = (int)e0;
        int c1 = (int)e1;
        float w0 = __int_as_float((int)(e0 >> 32));
        float w1 = has1 ? __int_as_float((int)(e1 >> 32)) : 0.f;

        if (INF == 0) {
            const uint4* p0 = (const uint4*)((const char*)zin + (((size_t)(uint)c0) << 8) + (lq << 4));
            const uint4* p1 = (const uint4*)((const char*)zin + (((size_t)(uint)c1) << 8) + (lq << 4));
            uint4 g0 = *p0;
            uint4 g1 = *p1;
            a0 += w0 * blo(g0.x); a1 += w0 * bhi(g0.x);
            a2 += w0 * blo(g0.y); a3 += w0 * bhi(g0.y);
            a4 += w0 * blo(g0.z); a5 += w0 * bhi(g0.z);
            a6 += w0 * blo(g0.w); a7 += w0 * bhi(g0.w);
            a0 += w1 * blo(g1.x); a1 += w1 * bhi(g1.x);
            a2 += w1 * blo(g1.y); a3 += w1 * bhi(g1.y);
            a4 += w1 * blo(g1.z); a5 += w1 * bhi(g1.z);
            a6 += w1 * blo(g1.w); a7 += w1 * bhi(g1.w);
        } else {
            unsigned long long g0 = *(const unsigned long long*)((const char*)zin + (((size_t)(uint)c0) << 7) + (lq << 3));
            unsigned long long g1 = *(const unsigned long long*)((const char*)zin + (((size_t)(uint)c1) << 7) + (lq << 3));
            uint g0x = (uint)g0, g0y = (uint)(g0 >> 32);
            uint g1x = (uint)g1, g1y = (uint)(g1 >> 32);
            auto f00 = __builtin_amdgcn_cvt_pk_f32_fp8((int)g0x, false);
            auto f01 = __builtin_amdgcn_cvt_pk_f32_fp8((int)g0x, true);
            auto f02 = __builtin_amdgcn_cvt_pk_f32_fp8((int)g0y, false);
            auto f03 = __builtin_amdgcn_cvt_pk_f32_fp8((int)g0y, true);
            a0 += w0 * f00[0]; a1 += w0 * f00[1];
            a2 += w0 * f01[0]; a3 += w0 * f01[1];
            a4 += w0 * f02[0]; a5 += w0 * f02[1];
            a6 += w0 * f03[0]; a7 += w0 * f03[1];
            auto f10 = __builtin_amdgcn_cvt_pk_f32_fp8((int)g1x, false);
            auto f11 = __builtin_amdgcn_cvt_pk_f32_fp8((int)g1x, true);
            auto f12 = __builtin_amdgcn_cvt_pk_f32_fp8((int)g1y, false);
            auto f13 = __builtin_amdgcn_cvt_pk_f32_fp8((int)g1y, true);
            a0 += w1 * f10[0]; a1 += w1 * f10[1];
            a2 += w1 * f11[0]; a3 += w1 * f11[1];
            a4 += w1 * f12[0]; a5 += w1 * f12[1];
            a6 += w1 * f13[0]; a7 += w1 * f13[1];
        }
    }

    float ds = dscale[n];
    const unsigned long long* hrow = (const unsigned long long*)((const char*)hp + (((size_t)n) << 8) + (lq << 4));
    unsigned long long h0 = __builtin_nontemporal_load(hrow);
    unsigned long long h1 = __builtin_nontemporal_load(hrow + 1);
    uint hx = (uint)h0, hy = (uint)(h0 >> 32), hz = (uint)h1, hw = (uint)(h1 >> 32);
    float o0 = a0 * ds + blo(hx), o1 = a1 * ds + bhi(hx);
    float o2 = a2 * ds + blo(hy), o3 = a3 * ds + bhi(hy);
    float o4 = a4 * ds + blo(hz), o5 = a5 * ds + bhi(hz);
    float o6 = a6 * ds + blo(hw), o7 = a7 * ds + bhi(hw);

    if (OUTF == 0) {
        unsigned long long* orow = (unsigned long long*)((char*)zout + (((size_t)n) << 8) + (lq << 4));
        unsigned long long u0 = (unsigned long long)pkbf(o0, o1) | ((unsigned long long)pkbf(o2, o3) << 32);
        unsigned long long u1 = (unsigned long long)pkbf(o4, o5) | ((unsigned long long)pkbf(o6, o7) << 32);
        __builtin_nontemporal_store(u0, orow);
        __builtin_nontemporal_store(u1, orow + 1);
    } else {
        int p0 = __builtin_amdgcn_cvt_pk_fp8_f32(o0, o1, 0, false);
        p0 = __builtin_amdgcn_cvt_pk_fp8_f32(o2, o3, p0, true);
        int p1 = __builtin_amdgcn_cvt_pk_fp8_f32(o4, o5, 0, false);
        p1 = __builtin_amdgcn_cvt_pk_fp8_f32(o6, o7, p1, true);
        unsigned long long u = (unsigned long long)(uint)p0 | ((unsigned long long)(uint)p1 << 32);
        unsigned long long* orow = (unsigned long long*)((char*)zout + (((size_t)n) << 7) + (lq << 3));
        __builtin_nontemporal_store(u, orow);
    }
}

// ---------------- pool over sorted batch (bf16 input, fp32 atomic out) ----------------
__global__ __launch_bounds__(64) void pool_kernel(const uint* __restrict__ z, const void* __restrict__ batchv,
                                                  const int* __restrict__ flag, float* __restrict__ gpool, int n) {
    const int l = threadIdx.x;
    int n0 = blockIdx.x * 64;
    int n1 = min(n0 + 64, n);
    int is64 = *flag;
    float rx = 0.f, ry = 0.f;
    int cur = -1;
    for (int i = n0; i < n1; i++) {
        int b = load_idx(batchv, i, is64);
        if (b != cur) {
            if (cur >= 0) {
                atomicAdd(&gpool[cur * HD + 2 * l], rx);
                atomicAdd(&gpool[cur * HD + 2 * l + 1], ry);
            }
            rx = 0.f; ry = 0.f;
            cur = b;
        }
        uint zb = z[(size_t)i * 64 + l];
        rx += blo(zb);
        ry += bhi(zb);
    }
    if (cur >= 0) {
        atomicAdd(&gpool[cur * HD + 2 * l], rx);
        atomicAdd(&gpool[cur * HD + 2 * l + 1], ry);
    }
}

// ---------------- graph head: 2x FC + final + log_softmax (fp32) ----------------
__global__ __launch_bounds__(128) void graph_kernel(const float* __restrict__ gpool, const float* __restrict__ gfc_w,
                                                    const float* __restrict__ gfc_b, const float* __restrict__ fw,
                                                    const float* __restrict__ fb, float* __restrict__ out) {
    __shared__ float buf[HD];
    __shared__ float o[10];
    __shared__ float ls;
    const int g = blockIdx.x, t = threadIdx.x;
    buf[t] = gpool[g * HD + t];
    __syncthreads();
    for (int L = 0; L < 2; L++) {
        const float* w = gfc_w + L * HD * HD;
        float s = gfc_b[L * HD + t];
        for (int k = 0; k < HD; k++) s += buf[k] * w[k * HD + t];
        s = fmaxf(s, 0.f);
        __syncthreads();
        buf[t] = s;
        __syncthreads();
    }
    if (t < 10) {
        float s = fb[t];
        for (int k = 0; k < HD; k++) s += buf[k] * fw[k * 10 + t];
        o[t] = s;
    }
    __syncthreads();
    if (t == 0) {
        float m = o[0];
        for (int i = 1; i < 10; i++) m = fmaxf(m, o[i]);
        float se = 0.f;
        for (int i = 0; i < 10; i++) se += expf(o[i] - m);
        ls = m + logf(se);
    }
    __syncthreads();
    if (t < 10) out[g * 10 + t] = o[t] - ls;
}

extern "C" void kernel_launch(void* const* d_in, const int* in_sizes, int n_in,
                              void* d_out, int out_size, void* d_ws, size_t ws_size,
                              hipStream_t stream) {
    const float* x = (const float*)d_in[0];
    const void* eiv = d_in[1];
    const float* ew = (const float*)d_in[2];
    const void* batchv = d_in[3];
    const float* mlp_w1 = (const float*)d_in[4];
    const float* mlp_b1 = (const float*)d_in[5];
    const float* mlp_w2 = (const float*)d_in[6];
    const float* mlp_b2 = (const float*)d_in[7];
    const float* mlp_w3 = (const float*)d_in[8];
    const float* mlp_b3 = (const float*)d_in[9];
    const float* bn_g = (const float*)d_in[10];
    const float* bn_b = (const float*)d_in[11];
    const float* bn_m = (const float*)d_in[12];
    const float* bn_v = (const float*)d_in[13];
    const float* fc_w = (const float*)d_in[14];
    const float* fc_b = (const float*)d_in[15];
    const float* gfc_w = (const float*)d_in[16];
    const float* gfc_b = (const float*)d_in[17];
    const float* fin_w = (const float*)d_in[18];
    const float* fin_b = (const float*)d_in[19];
    float* out = (float*)d_out;

    char* ws = (char*)d_ws;
    size_t off = 0;
    auto alloc = [&](size_t bytes) -> void* {
        void* p = ws + off;
        off = (off + bytes + 255) & ~(size_t)255;
        return p;
    };
    // persistent-through-deq
    ushort* hpb = (ushort*)alloc((size_t)NN * HD * 2);        // hp bf16 (25.6MB)
    ushort* za  = (ushort*)alloc((size_t)NN * HD * 2);        // final z bf16 (25.6MB)
    int2* edges = (int2*)alloc((size_t)NE * 8);               // CSR edges (12.8MB)
    // region1: fp8 z double buffer (12.8+12.8) ∪ bfA (25.6)
    char* region1 = (char*)alloc((size_t)NN * HD * 2);
    ushort* zf8a = (ushort*)region1;
    ushort* zf8b = (ushort*)(region1 + (size_t)NN * HD);
    ushort* bfA = (ushort*)region1;
    // region2: brow(1.6)+bcw(12.8) ∪ bfB (25.6)
    char* region2 = (char*)alloc((size_t)NN * HD * 2);
    unsigned char* brow = (unsigned char*)region2;
    int2* bcw = (int2*)(region2 + ((size_t)NE + 256));
    ushort* bfB = (ushort*)region2;
    // small stuff
    int* rowptr = (int*)alloc((size_t)(NN + 1) * 4);
    float* dscale = (float*)alloc((size_t)NN * 4);
    int* bcnt = (int*)alloc((size_t)NBUK * 4);
    int* bstart = (int*)alloc((size_t)(NBUK + 1) * 4);
    int* bcur = (int*)alloc((size_t)NBUK * 4);
    float* gpool = (float*)alloc((size_t)NG * HD * 4);
    int* flag = (int*)alloc(256);
    ushort* w1t = (ushort*)alloc(128 * 64 * 2);
    ushort* w2t = (ushort*)alloc(64 * 128 * 2);
    ushort* w3t = (ushort*)alloc(128 * 128 * 2);
    ushort* f1t = (ushort*)alloc(128 * 128 * 2);
    ushort* f2t = (ushort*)alloc(128 * 128 * 2);

    hipMemsetAsync(bcnt, 0, (size_t)NBUK * 4, stream);
    hipMemsetAsync(gpool, 0, (size_t)NG * HD * 4, stream);

    detect_kernel<<<1, 64, 0, stream>>>((const unsigned*)eiv, flag);
    // CSR build (bucketed, atomic-light)
    bkt_count<<<256, 256, 0, stream>>>(eiv, flag, bcnt, NE);
    bucket_scan<<<1, 1024, 0, stream>>>(bcnt, bstart, bcur);
    bkt_scatter<<<256, 256, 0, stream>>>(eiv, ew, flag, bcur, brow, bcw, NE);
    bkt_finalize<<<NBUK, 256, 0, stream>>>(bstart, brow, bcw, rowptr, edges, dscale, NE);

    // weight prep (bf16, transposed, pre-swizzled)
    wprep<<<64, 128, 0, stream>>>(mlp_w1, w1t, 128, 64);
    wprep<<<128, 64, 0, stream>>>(mlp_w2, w2t, 64, 128);
    wprep<<<128, 128, 0, stream>>>(mlp_w3, w3t, 128, 128);
    wprep<<<128, 128, 0, stream>>>(fc_w, f1t, 128, 128);
    wprep<<<128, 128, 0, stream>>>(fc_w + 128 * 128, f2t, 128, 128);

    const int GB = (NN + 63) / 64;
    // MLP encoder: x -> relu -> relu -> BN*0.5 = hp
    mgemm<128, 64, 0, true><<<GB, 256, 0, stream>>>(x, w1t, mlp_b1, bfA, NN, nullptr, nullptr, nullptr, nullptr);
    mgemm<64, 128, 0, false><<<GB, 256, 0, stream>>>(bfA, w2t, mlp_b2, bfB, NN, nullptr, nullptr, nullptr, nullptr);
    mgemm<128, 128, 1, false><<<GB, 256, 0, stream>>>(bfB, w3t, mlp_b3, hpb, NN, bn_g, bn_b, bn_m, bn_v);

    // DEQ: z1 = hp (analytic). 9 propagation steps: bf16->fp8, fp8->fp8 x7, fp8->bf16
    const int DB = NN / 16;  // 6250 blocks, 16 nodes per block (4/wave)
    deq_step<0, 1><<<DB, 256, 0, stream>>>(hpb, zf8a, (const uint*)hpb, dscale, rowptr, (const long long*)edges);
    {
        ushort* bufs[2] = {zf8a, zf8b};
        for (int it = 1; it <= 7; it++) {
            deq_step<1, 1><<<DB, 256, 0, stream>>>(bufs[(it + 1) & 1], bufs[it & 1], (const uint*)hpb,
                                                   dscale, rowptr, (const long long*)edges);
        }
    }
    deq_step<1, 0><<<DB, 256, 0, stream>>>(zf8b, za, (const uint*)hpb, dscale, rowptr, (const long long*)edges);

    // node FC stack
    mgemm<128, 128, 0, false><<<GB, 256, 0, stream>>>(za, f1t, fc_b, bfA, NN, nullptr, nullptr, nullptr, nullptr);
    mgemm<128, 128, 0, false><<<GB, 256, 0, stream>>>(bfA, f2t, fc_b + 128, bfB, NN, nullptr, nullptr, nullptr, nullptr);

    pool_kernel<<<(NN + 63) / 64, 64, 0, stream>>>((const uint*)bfB, batchv, flag, gpool, NN);
    graph_kernel<<<NG, 128, 0, stream>>>(gpool, gfc_w, gfc_b, fin_w, fin_b, out);
}